// Round 17
// baseline (175.713 us; speedup 1.0000x reference)
//
#include <hip/hip_runtime.h>

typedef float f32x4 __attribute__((ext_vector_type(4)));
typedef unsigned short u16;
typedef __attribute__((ext_vector_type(8))) unsigned short u16x8;

// ---------- helpers ----------
__device__ __forceinline__ u16 f2bf(float f) {
  unsigned u = __float_as_uint(f);
  u += 0x7FFFu + ((u >> 16) & 1u);   // round-to-nearest-even
  return (u16)(u >> 16);
}
__device__ __forceinline__ float bf2f(u16 h) { return __uint_as_float(((unsigned)h) << 16); }

__device__ __forceinline__ void mfma16(f32x4 a, f32x4 b, f32x4& c) {
  asm("v_mfma_f32_16x16x32_bf16 %0, %1, %2, %0" : "+v"(c) : "v"(a), "v"(b));
}

__device__ __forceinline__ void gload16(const u16* g, const u16* l) {
  __builtin_amdgcn_global_load_lds(
      (const __attribute__((address_space(1))) void*)g,
      (__attribute__((address_space(3))) void*)l, 16, 0, 0);
}

// Tiled GEMM-operand layout (u16): [tile=r/128][ktile=k/32][chunk=(k%32)/8][r%128][k%8]
__device__ __forceinline__ size_t tiled_off(int r, int k) {
  return (size_t)(r >> 7) * 98304 + (size_t)(k >> 5) * 4096 +
         (size_t)((k & 31) >> 3) * 1024 + (size_t)(r & 127) * 8 + (k & 7);
}

// ---------- prep: x -> tiled bf16 hi/lo ----------
__global__ __launch_bounds__(256) void prep_tile_x(const float* __restrict__ x,
                                                   u16* __restrict__ xh,
                                                   u16* __restrict__ xl) {
  const int lane = threadIdx.x & 63;
  const int wid = threadIdx.x >> 6;
  const int row = blockIdx.x * 64 + lane;     // 0..8191
  const int ktile = blockIdx.y * 4 + wid;     // 0..23
  const float4* src = reinterpret_cast<const float4*>(x + (size_t)row * 768 + ktile * 32);
  float4 f[8];
#pragma unroll
  for (int i = 0; i < 8; ++i) f[i] = src[i];
  const size_t base = (size_t)(row >> 7) * 98304 + (size_t)ktile * 4096 + (size_t)(row & 127) * 8;
#pragma unroll
  for (int c = 0; c < 4; ++c) {
    const float v[8] = {f[2 * c].x, f[2 * c].y, f[2 * c].z, f[2 * c].w,
                        f[2 * c + 1].x, f[2 * c + 1].y, f[2 * c + 1].z, f[2 * c + 1].w};
    u16x8 h, l;
#pragma unroll
    for (int e = 0; e < 8; ++e) {
      const u16 hb = f2bf(v[e]);
      h[e] = hb;
      l[e] = f2bf(v[e] - bf2f(hb));
    }
    *(u16x8*)(xh + base + c * 1024) = h;
    *(u16x8*)(xl + base + c * 1024) = l;
  }
}

// ---------- prep: W [768 x Ncols] -> tiled W^T (n as row), split hi/lo ----------
template <int WRITE_LO>
__global__ __launch_bounds__(256) void prep_wt(const float* __restrict__ W,
                                               u16* __restrict__ Wth,
                                               u16* __restrict__ Wtl, int Ncols) {
  int t = blockIdx.x * 256 + threadIdx.x;
  int total = Ncols * 192;
  if (t >= total) return;
  int n = t % Ncols;
  int k4 = t / Ncols;
  const int k0 = k4 * 4;
  u16 hh[4], ll[4];
#pragma unroll
  for (int j = 0; j < 4; ++j) {
    float v = W[(size_t)(k0 + j) * Ncols + n];
    hh[j] = f2bf(v);
    ll[j] = f2bf(v - bf2f(hh[j]));
  }
  const size_t dst = tiled_off(n, k0);
  ushort4 h4; h4.x = hh[0]; h4.y = hh[1]; h4.z = hh[2]; h4.w = hh[3];
  *reinterpret_cast<ushort4*>(Wth + dst) = h4;
  if (WRITE_LO) {
    ushort4 l4v; l4v.x = ll[0]; l4v.y = ll[1]; l4v.z = ll[2]; l4v.w = ll[3];
    *reinterpret_cast<ushort4*>(Wtl + dst) = l4v;
  }
}

// ---------- GEMM core (R8-proven): 128x128, BK=32, single-buffer, tiled operands ----------
template <int SPLIT>
__device__ __forceinline__ void gemm_core(u16* lds,
                                          const u16* __restrict__ Ah, const u16* __restrict__ Al,
                                          const u16* __restrict__ Bh, const u16* __restrict__ Bl,
                                          int Kdim, int rowBase, int colBase, f32x4 acc[4][4]) {
  const int tid = threadIdx.x;
  const int lane = tid & 63;
  const int wid = tid >> 6;
  const int wr = wid >> 1, wc = wid & 1;
  const int l15 = lane & 15, l4 = lane >> 4;
  const size_t aT = (size_t)(rowBase >> 7) * 98304;
  const size_t bT = (size_t)(colBase >> 7) * 98304;
  const int nk = Kdim >> 5;

  for (int kt = 0; kt < nk; ++kt) {
#pragma unroll
    for (int j = 0; j < 2; ++j) {
      const int i = wid * 2 + j;
      const size_t off = (size_t)kt * 4096 + i * 512 + lane * 8;
      gload16(Ah + aT + off, lds + i * 512);
      gload16(Bh + bT + off, lds + 4096 + i * 512);
      if constexpr (SPLIT) {
        gload16(Al + aT + off, lds + 8192 + i * 512);
        gload16(Bl + bT + off, lds + 12288 + i * 512);
      }
    }
    __syncthreads();

    f32x4 fah[4], fbh[4], fal[4], fbl[4];
#pragma unroll
    for (int mi = 0; mi < 4; ++mi) {
      const int row = wr * 64 + mi * 16 + l15;
      fah[mi] = *(const f32x4*)(lds + (l4 * 128 + row) * 8);
      if constexpr (SPLIT) fal[mi] = *(const f32x4*)(lds + 8192 + (l4 * 128 + row) * 8);
    }
#pragma unroll
    for (int nj = 0; nj < 4; ++nj) {
      const int col = wc * 64 + nj * 16 + l15;
      fbh[nj] = *(const f32x4*)(lds + 4096 + (l4 * 128 + col) * 8);
      if constexpr (SPLIT) fbl[nj] = *(const f32x4*)(lds + 12288 + (l4 * 128 + col) * 8);
    }
#pragma unroll
    for (int mi = 0; mi < 4; ++mi)
#pragma unroll
      for (int nj = 0; nj < 4; ++nj) {
        mfma16(fah[mi], fbh[nj], acc[mi][nj]);
        if constexpr (SPLIT) {
          mfma16(fah[mi], fbl[nj], acc[mi][nj]);
          mfma16(fal[mi], fbh[nj], acc[mi][nj]);
        }
      }
    __syncthreads();
  }
}

// ---------- QKV GEMM ----------
__global__ __launch_bounds__(256) void gemm_qkv_kernel(
    const u16* __restrict__ xh, const u16* __restrict__ xl,
    const u16* __restrict__ Wqh, const u16* __restrict__ Wql,
    u16* __restrict__ Qh, u16* __restrict__ Ql,
    u16* __restrict__ Kh, u16* __restrict__ Kl,
    u16* __restrict__ Vt) {
  __shared__ u16 lds[16384];
  const int rowBase = blockIdx.x * 128;
  const int colBase = blockIdx.y * 128;
  const int tid = threadIdx.x, lane = tid & 63, wid = tid >> 6;
  const int wr = wid >> 1, wc = wid & 1, l15 = lane & 15, l4 = lane >> 4;
  const int which = colBase / 768;
  const int cb = colBase % 768;

  f32x4 acc[4][4];
#pragma unroll
  for (int a = 0; a < 4; ++a)
#pragma unroll
    for (int b = 0; b < 4; ++b) acc[a][b] = (f32x4){0.f, 0.f, 0.f, 0.f};

  if (which == 2) {
    gemm_core<0>(lds, xh, nullptr, Wqh, nullptr, 768, rowBase, colBase, acc);
#pragma unroll
    for (int mi = 0; mi < 4; ++mi) {
#pragma unroll
      for (int nj = 0; nj < 4; ++nj) {
        const int crem = cb + wc * 64 + nj * 16 + l15;
        const int h = crem >> 6, d = crem & 63;
        const int rg0 = rowBase + wr * 64 + mi * 16 + l4 * 4;
        const int b = rg0 >> 10, s0 = rg0 & 1023;
        const int bh = b * 12 + h;
        ushort4 st;
        st.x = f2bf(acc[mi][nj][0]); st.y = f2bf(acc[mi][nj][1]);
        st.z = f2bf(acc[mi][nj][2]); st.w = f2bf(acc[mi][nj][3]);
        *reinterpret_cast<ushort4*>(Vt + (((size_t)(bh * 64 + d)) << 10) + s0) = st;
      }
    }
  } else {
    gemm_core<1>(lds, xh, xl, Wqh, Wql, 768, rowBase, colBase, acc);
    u16* dsth = (which == 0) ? Qh : Kh;
    u16* dstl = (which == 0) ? Ql : Kl;
#pragma unroll
    for (int mi = 0; mi < 4; ++mi) {
#pragma unroll
      for (int nj = 0; nj < 4; ++nj) {
        const int crem = cb + wc * 64 + nj * 16 + l15;
        const int h = crem >> 6, d = crem & 63;
        const int rg0 = rowBase + wr * 64 + mi * 16 + l4 * 4;
        const int b = rg0 >> 10, s0 = rg0 & 1023;
        const int bh = b * 12 + h;
#pragma unroll
        for (int r = 0; r < 4; ++r) {
          const float v = acc[mi][nj][r];
          const size_t idx = ((((size_t)bh) << 10) + s0 + r) * 64 + d;
          const u16 hb = f2bf(v);
          dsth[idx] = hb;
          dstl[idx] = f2bf(v - bf2f(hb));
        }
      }
    }
  }
}

// ---------- attention v5 (R11 pipeline, 4-wave blocks): 16 q-tiles of 64 rows,
// paired {p, 15-p} -> uniform 17 iters; grid 96x8 = 768 blocks = 3 per CU exactly
// (fixes the 384-blocks-on-256-CUs 75% balance). STAGE = 6 gloads (2 chunks per
// matrix per wave), counted vmcnt(6). LDS 56KB -> 2 blocks/CU. Softmax stays on
// __expf + x8-scale (exp2-domain rewrite failed numerics, R12-R15 — do not retry).
__global__ __launch_bounds__(256, 2) void attn_kernel(
    const u16* __restrict__ Qh, const u16* __restrict__ Ql,
    const u16* __restrict__ Kh, const u16* __restrict__ Kl,
    const u16* __restrict__ Vt, u16* __restrict__ attnO) {
  const int bh = blockIdx.x;     // 0..95  (bh-major -> same-bh blocks share an XCD)
  const int pair = blockIdx.y;   // 0..7
  const int tid = threadIdx.x, lane = tid & 63, w = tid >> 6;   // w = 0..3
  const int l15 = lane & 15, l4 = lane >> 4;
  __shared__ u16 kv[2][12288];   // per buf: Kh[0..4095] Kl[4096..8191] Vt[8192..12287]
  __shared__ u16 plds[4][1024];  // per-wave private 16x64 bf16 P, XOR-swizzled
  u16* pl = plds[w];

  const int qt0 = pair, qt1 = 15 - pair;   // 64-row q-tiles
  const int n0 = qt0 + 1;
  const int ntot = 17;

  const int srow = lane >> 3;
  const int schunk = (lane & 7) ^ srow;
  const int kr0 = w * 16 + srow;           // rows staged by this wave: kr0, kr0+8
  const int kr1 = kr0 + 8;

  f32x4 qfh[2], qfl[2], o[4];
  float m[4], ls[4];

#define STAGE(BSEL, KT)                                                                   \
  do {                                                                                    \
    u16* buf_ = kv[(BSEL)];                                                               \
    const size_t g0 = (size_t)(bh * 1024 + (KT) * 64 + kr0) * 64 + schunk * 8;            \
    const size_t g1 = (size_t)(bh * 1024 + (KT) * 64 + kr1) * 64 + schunk * 8;            \
    gload16(Kh + g0, buf_ + (w * 2) * 512);                                               \
    gload16(Kh + g1, buf_ + (w * 2 + 1) * 512);                                           \
    gload16(Kl + g0, buf_ + 4096 + (w * 2) * 512);                                        \
    gload16(Kl + g1, buf_ + 4096 + (w * 2 + 1) * 512);                                    \
    gload16(Vt + (size_t)(bh * 64 + kr0) * 1024 + (KT) * 64 + schunk * 8,                 \
            buf_ + 8192 + (w * 2) * 512);                                                 \
    gload16(Vt + (size_t)(bh * 64 + kr1) * 1024 + (KT) * 64 + schunk * 8,                 \
            buf_ + 8192 + (w * 2 + 1) * 512);                                             \
  } while (0)

  STAGE(0, 0);

  for (int i = 0; i < ntot; ++i) {
    const int seg = (i >= n0) ? 1 : 0;
    const int kt = seg ? (i - n0) : i;
    const int qt = seg ? qt1 : qt0;
    const int qb = qt * 64 + w * 16;   // this wave's 16 q-rows
    const int nseg = seg ? (ntot - n0) : n0;

    if (i + 1 < ntot) {
      const int seg2 = (i + 1 >= n0) ? 1 : 0;
      const int kt2 = seg2 ? (i + 1 - n0) : (i + 1);
      STAGE((i + 1) & 1, kt2);
      asm volatile("s_waitcnt vmcnt(6)" ::: "memory");
    } else {
      asm volatile("s_waitcnt vmcnt(0)" ::: "memory");
    }
    __builtin_amdgcn_s_barrier();

    if (kt == 0) {
#pragma unroll
      for (int ks = 0; ks < 2; ++ks) {
        const size_t off = ((size_t)(bh * 1024 + qb + l15)) * 64 + ks * 32 + l4 * 8;
        qfh[ks] = *(const f32x4*)(Qh + off);
        qfl[ks] = *(const f32x4*)(Ql + off);
      }
#pragma unroll
      for (int n = 0; n < 4; ++n) o[n] = (f32x4){0.f, 0.f, 0.f, 0.f};
#pragma unroll
      for (int r = 0; r < 4; ++r) { m[r] = -1e30f; ls[r] = 0.f; }
    }

    if (kt * 64 <= qb + 15) {
      const u16* buf = kv[i & 1];
      f32x4 sv[4];
#pragma unroll
      for (int n = 0; n < 4; ++n) sv[n] = (f32x4){0.f, 0.f, 0.f, 0.f};
      const int rsw = l15 & 7;
      __builtin_amdgcn_s_setprio(1);
#pragma unroll
      for (int nt = 0; nt < 4; ++nt) {
        const int row = nt * 16 + l15;
#pragma unroll
        for (int ks = 0; ks < 2; ++ks) {
          const int kc = ks * 4 + l4;
          const int off = row * 64 + ((kc ^ rsw) << 3);
          f32x4 kfh = *(const f32x4*)(buf + off);
          f32x4 kfl = *(const f32x4*)(buf + 4096 + off);
          mfma16(qfh[ks], kfh, sv[nt]);
          mfma16(qfh[ks], kfl, sv[nt]);
          mfma16(qfl[ks], kfh, sv[nt]);
        }
      }
      __builtin_amdgcn_s_setprio(0);
      const bool diag = (kt * 64 + 63 > qb);
#pragma unroll
      for (int nt = 0; nt < 4; ++nt) {
#pragma unroll
        for (int r = 0; r < 4; ++r) {
          float xv = sv[nt][r] * 8.0f;
          if (diag) {
            const int kg = kt * 64 + nt * 16 + l15;
            const int qg = qb + l4 * 4 + r;
            if (kg > qg) xv = -1e30f;
          }
          sv[nt][r] = xv;
        }
      }
#pragma unroll
      for (int r = 0; r < 4; ++r) {
        float mx = fmaxf(fmaxf(sv[0][r], sv[1][r]), fmaxf(sv[2][r], sv[3][r]));
#pragma unroll
        for (int dd = 1; dd < 16; dd <<= 1) mx = fmaxf(mx, __shfl_xor(mx, dd));
        const float mnew = fmaxf(m[r], mx);
        const float alpha = __expf(m[r] - mnew);
        float ps = 0.f;
#pragma unroll
        for (int nt = 0; nt < 4; ++nt) {
          const float p = __expf(sv[nt][r] - mnew);
          sv[nt][r] = p;
          ps += p;
        }
#pragma unroll
        for (int dd = 1; dd < 16; dd <<= 1) ps += __shfl_xor(ps, dd);
        ls[r] = ls[r] * alpha + ps;
        m[r] = mnew;
#pragma unroll
        for (int n = 0; n < 4; ++n) o[n][r] *= alpha;
      }
#pragma unroll
      for (int nt = 0; nt < 4; ++nt) {
#pragma unroll
        for (int r = 0; r < 4; ++r) {
          const int row = l4 * 4 + r;
          const int kcol = nt * 16 + l15;
          pl[row * 64 + ((((kcol >> 3) ^ (row & 7))) << 3) + (kcol & 7)] = f2bf(sv[nt][r]);
        }
      }
      __builtin_amdgcn_s_setprio(1);
#pragma unroll
      for (int ks = 0; ks < 2; ++ks) {
        const int kc = ks * 4 + l4;
        const f32x4 pa = *(const f32x4*)(pl + l15 * 64 + ((kc ^ (l15 & 7)) << 3));
#pragma unroll
        for (int nt2 = 0; nt2 < 4; ++nt2) {
          const int off = 8192 + (nt2 * 16 + l15) * 64 + ((kc ^ (l15 & 7)) << 3);
          const f32x4 vb = *(const f32x4*)(buf + off);
          mfma16(pa, vb, o[nt2]);
        }
      }
      __builtin_amdgcn_s_setprio(0);
    }
    __builtin_amdgcn_s_barrier();

    if (kt == nseg - 1) {
      const int b = bh / 12, h = bh % 12;
#pragma unroll
      for (int r = 0; r < 4; ++r) {
        const float inv = 1.0f / ls[r];
        const int qg = qb + l4 * 4 + r;
        const int rowg = b * 1024 + qg;
#pragma unroll
        for (int nt2 = 0; nt2 < 4; ++nt2) {
          const int colg = h * 64 + nt2 * 16 + l15;
          attnO[tiled_off(rowg, colg)] = f2bf(o[nt2][r] * inv);
        }
      }
    }
  }
#undef STAGE
}

// ---------- proj GEMM: out[8192,768] = attn @ W_proj + b (tiled A and B) ----------
__global__ __launch_bounds__(256) void gemm_proj_kernel(
    const u16* __restrict__ A, const u16* __restrict__ Bt,
    const float* __restrict__ bias, float* __restrict__ out) {
  __shared__ u16 lds[8192];
  f32x4 acc[4][4];
#pragma unroll
  for (int a = 0; a < 4; ++a)
#pragma unroll
    for (int b = 0; b < 4; ++b) acc[a][b] = (f32x4){0.f, 0.f, 0.f, 0.f};

  const int rowBase = blockIdx.x * 128;
  const int colBase = blockIdx.y * 128;
  gemm_core<0>(lds, A, nullptr, Bt, nullptr, 768, rowBase, colBase, acc);

  const int tid = threadIdx.x, lane = tid & 63, wid = tid >> 6;
  const int wr = wid >> 1, wc = wid & 1, l15 = lane & 15, l4 = lane >> 4;
#pragma unroll
  for (int mi = 0; mi < 4; ++mi) {
#pragma unroll
    for (int nj = 0; nj < 4; ++nj) {
      const int cg = colBase + wc * 64 + nj * 16 + l15;
      const float bv = bias[cg];
#pragma unroll
      for (int r = 0; r < 4; ++r) {
        const int rg = rowBase + wr * 64 + mi * 16 + l4 * 4 + r;
        out[(size_t)rg * 768 + cg] = acc[mi][nj][r] + bv;
      }
    }
  }
}

// ---------- launch ----------
extern "C" void kernel_launch(void* const* d_in, const int* in_sizes, int n_in,
                              void* d_out, int out_size, void* d_ws, size_t ws_size,
                              hipStream_t stream) {
  (void)in_sizes; (void)n_in; (void)out_size; (void)ws_size;
  const float* x = (const float*)d_in[0];
  const float* Wqkv = (const float*)d_in[1];
  const float* Wproj = (const float*)d_in[2];
  const float* bias = (const float*)d_in[3];
  float* out = (float*)d_out;
  char* ws = (char*)d_ws;

  u16* xh  = (u16*)(ws + 0);          // tiled; aliased as attn output later (also tiled)
  u16* xl  = (u16*)(ws + 12582912);
  u16* Wqh = (u16*)(ws + 25165824);
  u16* Wql = (u16*)(ws + 28704768);
  u16* Wph = (u16*)(ws + 32243712);
  u16* Qh  = (u16*)(ws + 33423360);   // [96,1024,64]
  u16* Ql  = (u16*)(ws + 46006272);
  u16* Kh  = (u16*)(ws + 58589184);
  u16* Kl  = (u16*)(ws + 71172096);
  u16* Vt  = (u16*)(ws + 83755008);   // [96,64,1024]
  u16* attn = xh;

  prep_tile_x<<<dim3(128, 6), dim3(256), 0, stream>>>(x, xh, xl);
  prep_wt<1><<<dim3(1728), dim3(256), 0, stream>>>(Wqkv, Wqh, Wql, 2304);
  prep_wt<0><<<dim3(576), dim3(256), 0, stream>>>(Wproj, Wph, (u16*)nullptr, 768);
  gemm_qkv_kernel<<<dim3(64, 18), dim3(256), 0, stream>>>(xh, xl, Wqh, Wql,
                                                          Qh, Ql, Kh, Kl, Vt);
  attn_kernel<<<dim3(96, 8), dim3(256), 0, stream>>>(Qh, Ql, Kh, Kl, Vt, attn);
  gemm_proj_kernel<<<dim3(64, 6), dim3(256), 0, stream>>>(attn, Wph, bias, out);
}

// Round 18
// 165.531 us; speedup vs baseline: 1.0615x; 1.0615x over previous
//
#include <hip/hip_runtime.h>

typedef float f32x4 __attribute__((ext_vector_type(4)));
typedef unsigned short u16;
typedef __attribute__((ext_vector_type(8))) unsigned short u16x8;

// ---------- helpers ----------
__device__ __forceinline__ u16 f2bf(float f) {
  unsigned u = __float_as_uint(f);
  u += 0x7FFFu + ((u >> 16) & 1u);   // round-to-nearest-even
  return (u16)(u >> 16);
}
__device__ __forceinline__ float bf2f(u16 h) { return __uint_as_float(((unsigned)h) << 16); }

__device__ __forceinline__ void mfma16(f32x4 a, f32x4 b, f32x4& c) {
  asm("v_mfma_f32_16x16x32_bf16 %0, %1, %2, %0" : "+v"(c) : "v"(a), "v"(b));
}

__device__ __forceinline__ void gload16(const u16* g, const u16* l) {
  __builtin_amdgcn_global_load_lds(
      (const __attribute__((address_space(1))) void*)g,
      (__attribute__((address_space(3))) void*)l, 16, 0, 0);
}

// Tiled GEMM-operand layout (u16): [tile=r/128][ktile=k/32][chunk=(k%32)/8][r%128][k%8]
__device__ __forceinline__ size_t tiled_off(int r, int k) {
  return (size_t)(r >> 7) * 98304 + (size_t)(k >> 5) * 4096 +
         (size_t)((k & 31) >> 3) * 1024 + (size_t)(r & 127) * 8 + (k & 7);
}

// ---------- prep: x -> tiled bf16 hi/lo ----------
__global__ __launch_bounds__(256) void prep_tile_x(const float* __restrict__ x,
                                                   u16* __restrict__ xh,
                                                   u16* __restrict__ xl) {
  const int lane = threadIdx.x & 63;
  const int wid = threadIdx.x >> 6;
  const int row = blockIdx.x * 64 + lane;     // 0..8191
  const int ktile = blockIdx.y * 4 + wid;     // 0..23
  const float4* src = reinterpret_cast<const float4*>(x + (size_t)row * 768 + ktile * 32);
  float4 f[8];
#pragma unroll
  for (int i = 0; i < 8; ++i) f[i] = src[i];
  const size_t base = (size_t)(row >> 7) * 98304 + (size_t)ktile * 4096 + (size_t)(row & 127) * 8;
#pragma unroll
  for (int c = 0; c < 4; ++c) {
    const float v[8] = {f[2 * c].x, f[2 * c].y, f[2 * c].z, f[2 * c].w,
                        f[2 * c + 1].x, f[2 * c + 1].y, f[2 * c + 1].z, f[2 * c + 1].w};
    u16x8 h, l;
#pragma unroll
    for (int e = 0; e < 8; ++e) {
      const u16 hb = f2bf(v[e]);
      h[e] = hb;
      l[e] = f2bf(v[e] - bf2f(hb));
    }
    *(u16x8*)(xh + base + c * 1024) = h;
    *(u16x8*)(xl + base + c * 1024) = l;
  }
}

// ---------- prep: W [768 x Ncols] -> tiled W^T (n as row), split hi/lo ----------
template <int WRITE_LO>
__global__ __launch_bounds__(256) void prep_wt(const float* __restrict__ W,
                                               u16* __restrict__ Wth,
                                               u16* __restrict__ Wtl, int Ncols) {
  int t = blockIdx.x * 256 + threadIdx.x;
  int total = Ncols * 192;
  if (t >= total) return;
  int n = t % Ncols;
  int k4 = t / Ncols;
  const int k0 = k4 * 4;
  u16 hh[4], ll[4];
#pragma unroll
  for (int j = 0; j < 4; ++j) {
    float v = W[(size_t)(k0 + j) * Ncols + n];
    hh[j] = f2bf(v);
    ll[j] = f2bf(v - bf2f(hh[j]));
  }
  const size_t dst = tiled_off(n, k0);
  ushort4 h4; h4.x = hh[0]; h4.y = hh[1]; h4.z = hh[2]; h4.w = hh[3];
  *reinterpret_cast<ushort4*>(Wth + dst) = h4;
  if (WRITE_LO) {
    ushort4 l4v; l4v.x = ll[0]; l4v.y = ll[1]; l4v.z = ll[2]; l4v.w = ll[3];
    *reinterpret_cast<ushort4*>(Wtl + dst) = l4v;
  }
}

// ---------- GEMM core (R8-proven): 128x128, BK=32, single-buffer, tiled operands ----------
template <int SPLIT>
__device__ __forceinline__ void gemm_core(u16* lds,
                                          const u16* __restrict__ Ah, const u16* __restrict__ Al,
                                          const u16* __restrict__ Bh, const u16* __restrict__ Bl,
                                          int Kdim, int rowBase, int colBase, f32x4 acc[4][4]) {
  const int tid = threadIdx.x;
  const int lane = tid & 63;
  const int wid = tid >> 6;
  const int wr = wid >> 1, wc = wid & 1;
  const int l15 = lane & 15, l4 = lane >> 4;
  const size_t aT = (size_t)(rowBase >> 7) * 98304;
  const size_t bT = (size_t)(colBase >> 7) * 98304;
  const int nk = Kdim >> 5;

  for (int kt = 0; kt < nk; ++kt) {
#pragma unroll
    for (int j = 0; j < 2; ++j) {
      const int i = wid * 2 + j;
      const size_t off = (size_t)kt * 4096 + i * 512 + lane * 8;
      gload16(Ah + aT + off, lds + i * 512);
      gload16(Bh + bT + off, lds + 4096 + i * 512);
      if constexpr (SPLIT) {
        gload16(Al + aT + off, lds + 8192 + i * 512);
        gload16(Bl + bT + off, lds + 12288 + i * 512);
      }
    }
    __syncthreads();

    f32x4 fah[4], fbh[4], fal[4], fbl[4];
#pragma unroll
    for (int mi = 0; mi < 4; ++mi) {
      const int row = wr * 64 + mi * 16 + l15;
      fah[mi] = *(const f32x4*)(lds + (l4 * 128 + row) * 8);
      if constexpr (SPLIT) fal[mi] = *(const f32x4*)(lds + 8192 + (l4 * 128 + row) * 8);
    }
#pragma unroll
    for (int nj = 0; nj < 4; ++nj) {
      const int col = wc * 64 + nj * 16 + l15;
      fbh[nj] = *(const f32x4*)(lds + 4096 + (l4 * 128 + col) * 8);
      if constexpr (SPLIT) fbl[nj] = *(const f32x4*)(lds + 12288 + (l4 * 128 + col) * 8);
    }
#pragma unroll
    for (int mi = 0; mi < 4; ++mi)
#pragma unroll
      for (int nj = 0; nj < 4; ++nj) {
        mfma16(fah[mi], fbh[nj], acc[mi][nj]);
        if constexpr (SPLIT) {
          mfma16(fah[mi], fbl[nj], acc[mi][nj]);
          mfma16(fal[mi], fbh[nj], acc[mi][nj]);
        }
      }
    __syncthreads();
  }
}

// ---------- QKV GEMM ----------
__global__ __launch_bounds__(256) void gemm_qkv_kernel(
    const u16* __restrict__ xh, const u16* __restrict__ xl,
    const u16* __restrict__ Wqh, const u16* __restrict__ Wql,
    u16* __restrict__ Qh, u16* __restrict__ Ql,
    u16* __restrict__ Kh, u16* __restrict__ Kl,
    u16* __restrict__ Vt) {
  __shared__ u16 lds[16384];
  const int rowBase = blockIdx.x * 128;
  const int colBase = blockIdx.y * 128;
  const int tid = threadIdx.x, lane = tid & 63, wid = tid >> 6;
  const int wr = wid >> 1, wc = wid & 1, l15 = lane & 15, l4 = lane >> 4;
  const int which = colBase / 768;
  const int cb = colBase % 768;

  f32x4 acc[4][4];
#pragma unroll
  for (int a = 0; a < 4; ++a)
#pragma unroll
    for (int b = 0; b < 4; ++b) acc[a][b] = (f32x4){0.f, 0.f, 0.f, 0.f};

  if (which == 2) {
    gemm_core<0>(lds, xh, nullptr, Wqh, nullptr, 768, rowBase, colBase, acc);
#pragma unroll
    for (int mi = 0; mi < 4; ++mi) {
#pragma unroll
      for (int nj = 0; nj < 4; ++nj) {
        const int crem = cb + wc * 64 + nj * 16 + l15;
        const int h = crem >> 6, d = crem & 63;
        const int rg0 = rowBase + wr * 64 + mi * 16 + l4 * 4;
        const int b = rg0 >> 10, s0 = rg0 & 1023;
        const int bh = b * 12 + h;
        ushort4 st;
        st.x = f2bf(acc[mi][nj][0]); st.y = f2bf(acc[mi][nj][1]);
        st.z = f2bf(acc[mi][nj][2]); st.w = f2bf(acc[mi][nj][3]);
        *reinterpret_cast<ushort4*>(Vt + (((size_t)(bh * 64 + d)) << 10) + s0) = st;
      }
    }
  } else {
    gemm_core<1>(lds, xh, xl, Wqh, Wql, 768, rowBase, colBase, acc);
    u16* dsth = (which == 0) ? Qh : Kh;
    u16* dstl = (which == 0) ? Ql : Kl;
#pragma unroll
    for (int mi = 0; mi < 4; ++mi) {
#pragma unroll
      for (int nj = 0; nj < 4; ++nj) {
        const int crem = cb + wc * 64 + nj * 16 + l15;
        const int h = crem >> 6, d = crem & 63;
        const int rg0 = rowBase + wr * 64 + mi * 16 + l4 * 4;
        const int b = rg0 >> 10, s0 = rg0 & 1023;
        const int bh = b * 12 + h;
#pragma unroll
        for (int r = 0; r < 4; ++r) {
          const float v = acc[mi][nj][r];
          const size_t idx = ((((size_t)bh) << 10) + s0 + r) * 64 + d;
          const u16 hb = f2bf(v);
          dsth[idx] = hb;
          dstl[idx] = f2bf(v - bf2f(hb));
        }
      }
    }
  }
}

// ---------- attention (R16-proven final): 8 waves x 16 q-rows, paired qt {p, 7-p},
// K(hi/lo)+V staged to LDS dbuf (vmcnt(3) counted wait), per-wave XOR-swizzled P LDS,
// bh-major grid (same-bh blocks share an XCD), s_setprio around MFMA clusters.
// Locked decisions (measured): softmax on __expf + x8-scale (exp2 rewrite fails
// numerics, R12-R15); 8-wave/512-thread blocks (4-wave grid-balance variant was
// -15% via occupancy, R17); V staged via LDS (direct-L2 was -2x, R10).
__global__ __launch_bounds__(512, 4) void attn_kernel(
    const u16* __restrict__ Qh, const u16* __restrict__ Ql,
    const u16* __restrict__ Kh, const u16* __restrict__ Kl,
    const u16* __restrict__ Vt, u16* __restrict__ attnO) {
  const int bh = blockIdx.x;     // 0..95
  const int pair = blockIdx.y;   // 0..3
  const int tid = threadIdx.x, lane = tid & 63, w = tid >> 6;
  const int l15 = lane & 15, l4 = lane >> 4;
  __shared__ u16 kv[2][12288];   // per buf: Kh[0..4095] Kl[4096..8191] Vt[8192..12287]
  __shared__ u16 plds[8][1024];  // per-wave private 16x64 bf16 P, XOR-swizzled
  u16* pl = plds[w];

  const int qt0 = pair, qt1 = 7 - pair;
  const int n0 = 2 * qt0 + 2;
  const int ntot = 18;

  const int srow = lane >> 3;
  const int schunk = (lane & 7) ^ srow;
  const int krow = w * 8 + srow;

  f32x4 qfh[2], qfl[2], o[4];
  float m[4], ls[4];

#define STAGE(BSEL, KT)                                                                   \
  do {                                                                                    \
    u16* buf_ = kv[(BSEL)];                                                               \
    const size_t kgo = (size_t)(bh * 1024 + (KT) * 64 + krow) * 64 + schunk * 8;          \
    gload16(Kh + kgo, buf_ + w * 512);                                                    \
    gload16(Kl + kgo, buf_ + 4096 + w * 512);                                             \
    gload16(Vt + (size_t)(bh * 64 + krow) * 1024 + (KT) * 64 + schunk * 8,                \
            buf_ + 8192 + w * 512);                                                       \
  } while (0)

  STAGE(0, 0);

  for (int i = 0; i < ntot; ++i) {
    const int seg = (i >= n0) ? 1 : 0;
    const int kt = seg ? (i - n0) : i;
    const int qt = seg ? qt1 : qt0;
    const int qb = qt * 128 + w * 16;
    const int nseg = seg ? (ntot - n0) : n0;

    if (i + 1 < ntot) {
      const int seg2 = (i + 1 >= n0) ? 1 : 0;
      const int kt2 = seg2 ? (i + 1 - n0) : (i + 1);
      STAGE((i + 1) & 1, kt2);
      asm volatile("s_waitcnt vmcnt(3)" ::: "memory");
    } else {
      asm volatile("s_waitcnt vmcnt(0)" ::: "memory");
    }
    __builtin_amdgcn_s_barrier();

    if (kt == 0) {
#pragma unroll
      for (int ks = 0; ks < 2; ++ks) {
        const size_t off = ((size_t)(bh * 1024 + qb + l15)) * 64 + ks * 32 + l4 * 8;
        qfh[ks] = *(const f32x4*)(Qh + off);
        qfl[ks] = *(const f32x4*)(Ql + off);
      }
#pragma unroll
      for (int n = 0; n < 4; ++n) o[n] = (f32x4){0.f, 0.f, 0.f, 0.f};
#pragma unroll
      for (int r = 0; r < 4; ++r) { m[r] = -1e30f; ls[r] = 0.f; }
    }

    if (kt * 64 <= qb + 15) {
      const u16* buf = kv[i & 1];
      f32x4 sv[4];
#pragma unroll
      for (int n = 0; n < 4; ++n) sv[n] = (f32x4){0.f, 0.f, 0.f, 0.f};
      const int rsw = l15 & 7;
      __builtin_amdgcn_s_setprio(1);
#pragma unroll
      for (int nt = 0; nt < 4; ++nt) {
        const int row = nt * 16 + l15;
#pragma unroll
        for (int ks = 0; ks < 2; ++ks) {
          const int kc = ks * 4 + l4;
          const int off = row * 64 + ((kc ^ rsw) << 3);
          f32x4 kfh = *(const f32x4*)(buf + off);
          f32x4 kfl = *(const f32x4*)(buf + 4096 + off);
          mfma16(qfh[ks], kfh, sv[nt]);
          mfma16(qfh[ks], kfl, sv[nt]);
          mfma16(qfl[ks], kfh, sv[nt]);
        }
      }
      __builtin_amdgcn_s_setprio(0);
      const bool diag = (kt * 64 + 63 > qb);
#pragma unroll
      for (int nt = 0; nt < 4; ++nt) {
#pragma unroll
        for (int r = 0; r < 4; ++r) {
          float xv = sv[nt][r] * 8.0f;
          if (diag) {
            const int kg = kt * 64 + nt * 16 + l15;
            const int qg = qb + l4 * 4 + r;
            if (kg > qg) xv = -1e30f;
          }
          sv[nt][r] = xv;
        }
      }
#pragma unroll
      for (int r = 0; r < 4; ++r) {
        float mx = fmaxf(fmaxf(sv[0][r], sv[1][r]), fmaxf(sv[2][r], sv[3][r]));
#pragma unroll
        for (int dd = 1; dd < 16; dd <<= 1) mx = fmaxf(mx, __shfl_xor(mx, dd));
        const float mnew = fmaxf(m[r], mx);
        const float alpha = __expf(m[r] - mnew);
        float ps = 0.f;
#pragma unroll
        for (int nt = 0; nt < 4; ++nt) {
          const float p = __expf(sv[nt][r] - mnew);
          sv[nt][r] = p;
          ps += p;
        }
#pragma unroll
        for (int dd = 1; dd < 16; dd <<= 1) ps += __shfl_xor(ps, dd);
        ls[r] = ls[r] * alpha + ps;
        m[r] = mnew;
#pragma unroll
        for (int n = 0; n < 4; ++n) o[n][r] *= alpha;
      }
#pragma unroll
      for (int nt = 0; nt < 4; ++nt) {
#pragma unroll
        for (int r = 0; r < 4; ++r) {
          const int row = l4 * 4 + r;
          const int kcol = nt * 16 + l15;
          pl[row * 64 + ((((kcol >> 3) ^ (row & 7))) << 3) + (kcol & 7)] = f2bf(sv[nt][r]);
        }
      }
      __builtin_amdgcn_s_setprio(1);
#pragma unroll
      for (int ks = 0; ks < 2; ++ks) {
        const int kc = ks * 4 + l4;
        const f32x4 pa = *(const f32x4*)(pl + l15 * 64 + ((kc ^ (l15 & 7)) << 3));
#pragma unroll
        for (int nt2 = 0; nt2 < 4; ++nt2) {
          const int off = 8192 + (nt2 * 16 + l15) * 64 + ((kc ^ (l15 & 7)) << 3);
          const f32x4 vb = *(const f32x4*)(buf + off);
          mfma16(pa, vb, o[nt2]);
        }
      }
      __builtin_amdgcn_s_setprio(0);
    }
    __builtin_amdgcn_s_barrier();

    if (kt == nseg - 1) {
      const int b = bh / 12, h = bh % 12;
#pragma unroll
      for (int r = 0; r < 4; ++r) {
        const float inv = 1.0f / ls[r];
        const int qg = qb + l4 * 4 + r;
        const int rowg = b * 1024 + qg;
#pragma unroll
        for (int nt2 = 0; nt2 < 4; ++nt2) {
          const int colg = h * 64 + nt2 * 16 + l15;
          attnO[tiled_off(rowg, colg)] = f2bf(o[nt2][r] * inv);
        }
      }
    }
  }
#undef STAGE
}

// ---------- proj GEMM: out[8192,768] = attn @ W_proj + b (tiled A and B) ----------
__global__ __launch_bounds__(256) void gemm_proj_kernel(
    const u16* __restrict__ A, const u16* __restrict__ Bt,
    const float* __restrict__ bias, float* __restrict__ out) {
  __shared__ u16 lds[8192];
  f32x4 acc[4][4];
#pragma unroll
  for (int a = 0; a < 4; ++a)
#pragma unroll
    for (int b = 0; b < 4; ++b) acc[a][b] = (f32x4){0.f, 0.f, 0.f, 0.f};

  const int rowBase = blockIdx.x * 128;
  const int colBase = blockIdx.y * 128;
  gemm_core<0>(lds, A, nullptr, Bt, nullptr, 768, rowBase, colBase, acc);

  const int tid = threadIdx.x, lane = tid & 63, wid = tid >> 6;
  const int wr = wid >> 1, wc = wid & 1, l15 = lane & 15, l4 = lane >> 4;
#pragma unroll
  for (int mi = 0; mi < 4; ++mi) {
#pragma unroll
    for (int nj = 0; nj < 4; ++nj) {
      const int cg = colBase + wc * 64 + nj * 16 + l15;
      const float bv = bias[cg];
#pragma unroll
      for (int r = 0; r < 4; ++r) {
        const int rg = rowBase + wr * 64 + mi * 16 + l4 * 4 + r;
        out[(size_t)rg * 768 + cg] = acc[mi][nj][r] + bv;
      }
    }
  }
}

// ---------- launch ----------
extern "C" void kernel_launch(void* const* d_in, const int* in_sizes, int n_in,
                              void* d_out, int out_size, void* d_ws, size_t ws_size,
                              hipStream_t stream) {
  (void)in_sizes; (void)n_in; (void)out_size; (void)ws_size;
  const float* x = (const float*)d_in[0];
  const float* Wqkv = (const float*)d_in[1];
  const float* Wproj = (const float*)d_in[2];
  const float* bias = (const float*)d_in[3];
  float* out = (float*)d_out;
  char* ws = (char*)d_ws;

  u16* xh  = (u16*)(ws + 0);          // tiled; aliased as attn output later (also tiled)
  u16* xl  = (u16*)(ws + 12582912);
  u16* Wqh = (u16*)(ws + 25165824);
  u16* Wql = (u16*)(ws + 28704768);
  u16* Wph = (u16*)(ws + 32243712);
  u16* Qh  = (u16*)(ws + 33423360);   // [96,1024,64]
  u16* Ql  = (u16*)(ws + 46006272);
  u16* Kh  = (u16*)(ws + 58589184);
  u16* Kl  = (u16*)(ws + 71172096);
  u16* Vt  = (u16*)(ws + 83755008);   // [96,64,1024]
  u16* attn = xh;

  prep_tile_x<<<dim3(128, 6), dim3(256), 0, stream>>>(x, xh, xl);
  prep_wt<1><<<dim3(1728), dim3(256), 0, stream>>>(Wqkv, Wqh, Wql, 2304);
  prep_wt<0><<<dim3(576), dim3(256), 0, stream>>>(Wproj, Wph, (u16*)nullptr, 768);
  gemm_qkv_kernel<<<dim3(64, 18), dim3(256), 0, stream>>>(xh, xl, Wqh, Wql,
                                                          Qh, Ql, Kh, Kl, Vt);
  attn_kernel<<<dim3(96, 4), dim3(512), 0, stream>>>(Qh, Ql, Kh, Kl, Vt, attn);
  gemm_proj_kernel<<<dim3(64, 6), dim3(256), 0, stream>>>(attn, Wph, bias, out);
}